// Round 3
// baseline (2148.649 us; speedup 1.0000x reference)
//
#include <hip/hip_runtime.h>
#include <stdint.h>

typedef unsigned int   u32;
typedef unsigned long long u64;

#define B_    8
#define S_    1024
#define HID_  1024
#define NH_   16
#define HD_   64
#define E_    8
#define IDIM_ 128
#define NTOK  (B_*NH_*S_)   /* 131072 */

// load/store 64 consecutive fp32 via 16x float4
__device__ __forceinline__ void loadf64(const float* __restrict__ p, float* r){
    #pragma unroll
    for (int i = 0; i < 16; i++){
        float4 t = ((const float4*)p)[i];
        r[i*4+0] = t.x; r[i*4+1] = t.y; r[i*4+2] = t.z; r[i*4+3] = t.w;
    }
}
__device__ __forceinline__ void storef64(float* p, const float* r){
    #pragma unroll
    for (int i = 0; i < 16; i++){
        float4 t; t.x = r[i*4+0]; t.y = r[i*4+1]; t.z = r[i*4+2]; t.w = r[i*4+3];
        ((float4*)p)[i] = t;
    }
}
// 64-dot: LDS weight row (float4 broadcast reads) x reg vector, 4 chains for ILP
__device__ __forceinline__ float dot64(const float* __restrict__ w, const float* __restrict__ g){
    float a0=0.f, a1=0.f, a2=0.f, a3=0.f;
    const float4* w4 = (const float4*)w;
    #pragma unroll
    for (int i = 0; i < 16; i++){
        float4 ww = w4[i];
        a0 += ww.x * g[i*4+0];
        a1 += ww.y * g[i*4+1];
        a2 += ww.z * g[i*4+2];
        a3 += ww.w * g[i*4+3];
    }
    return (a0+a1)+(a2+a3);
}
__device__ __forceinline__ float gelu_f(float x){
    return 0.5f * x * (1.0f + erff(x * 0.70710678118654752f));
}

// ---------------- kernel 1: k/v projection + memory cell -> current_memorys ----------------
__global__ __launch_bounds__(256,2) void k_mem(
    const float* __restrict__ kin, const float* __restrict__ vin, const float* __restrict__ mem,
    const float* __restrict__ Wk,  const float* __restrict__ Wv,  const float* __restrict__ fg,
    float* __restrict__ cur_out)
{
    __shared__ float sWk[4096], sWv[4096], sFG[64];
    const int tid = threadIdx.x;
    for (int i = tid; i < 4096; i += 256){ sWk[i] = Wk[i]; sWv[i] = Wv[i]; }
    if (tid < 64) sFG[tid] = fg[tid];
    __syncthreads();

    const int n = blockIdx.x*256 + tid;
    const int s = n & (S_-1), h = (n >> 10) & (NH_-1), b = n >> 14;
    const size_t go = ((size_t)(b*S_ + s))*HID_ + h*HD_;

    float k[64], v[64], mv[64];
    loadf64(kin + go, k);
    loadf64(vin + go, v);

    const size_t mo = (size_t)n * 64;
    loadf64(mem + mo, mv);

    float curv[64];
    #pragma unroll 8
    for (int d = 0; d < 64; d++){
        float kd = dot64(&sWk[d*64], k);
        float vd = dot64(&sWv[d*64], v);
        float f  = sFG[d];
        float cell = kd*vd + f*mv[d];
        curv[d] = (1.0f - f)*cell + f*mv[d];
    }
    storef64(cur_out + mo, curv);
}

// ---------------- kernel 2: q projection, x = q_*cur -> staged into out0 at final pos ----------------
__global__ __launch_bounds__(256,2) void k_q(
    const float* __restrict__ qin, const float* __restrict__ cur_in, const float* __restrict__ Wq,
    float* __restrict__ x_out)
{
    __shared__ float sWq[4096];
    const int tid = threadIdx.x;
    for (int i = tid; i < 4096; i += 256) sWq[i] = Wq[i];
    __syncthreads();

    const int n = blockIdx.x*256 + tid;
    const int s = n & (S_-1), h = (n >> 10) & (NH_-1), b = n >> 14;
    const size_t go = ((size_t)(b*S_ + s))*HID_ + h*HD_;

    float q[64], cu[64];
    loadf64(qin + go, q);

    const size_t mo  = (size_t)n * 64;                         // [B,NH,S,HD] token order
    const size_t pos = ((size_t)((b*S_ + s)*NH_ + h)) * 64;    // final out0 position for token n
    loadf64(cur_in + mo, cu);

    float xv[64];
    #pragma unroll 8
    for (int d = 0; d < 64; d++){
        float qd = dot64(&sWq[d*64], q);
        xv[d] = qd * cu[d];
    }
    storef64(x_out + pos, xv);
}

// ---------------- kernel 3: fused gate + top-2 MoE, in-place on out0 ----------------
// One thread per token. x read from out0[pos], result written back to out0[pos]
// (bijective token->pos, no cross-thread aliasing). All 8 experts looped with
// LDS-staged weights; threads predicate on membership in their top-2.
__global__ __launch_bounds__(256,2) void k_moe(
    const float* __restrict__ gW,  const float* __restrict__ gB,
    const float* __restrict__ W1,  const float* __restrict__ W2,
    const float* __restrict__ l1g, const float* __restrict__ l1b,
    const float* __restrict__ l2g, const float* __restrict__ l2b,
    const float* __restrict__ b2,  float* __restrict__ out0)
{
    __shared__ float sW1[8192], sW2T[8192];                 // 64 KB
    __shared__ float sL1g[64], sL1b[64], sL2g[128], sL2b[128], sB2[64];
    __shared__ float sGW[512], sGB[8];                      // total ~68 KB -> 2 blocks/CU
    const int tid = threadIdx.x;

    // stage gate weights (once)
    for (int i = tid; i < 512; i += 256) sGW[i] = gW[i];
    if (tid < 8) sGB[tid] = gB[tid];

    const int n = blockIdx.x*256 + tid;
    const int s = n & (S_-1), h = (n >> 10) & (NH_-1), b = n >> 14;
    const size_t pos = ((size_t)((b*S_ + s)*NH_ + h)) * 64;

    float x[64];
    loadf64(out0 + pos, x);
    __syncthreads();   // gate weights visible

    // gate logits from raw x
    float lg[8];
    #pragma unroll
    for (int e = 0; e < 8; e++) lg[e] = sGB[e];
    for (int d = 0; d < 64; d++){
        float xd = x[d];
        #pragma unroll
        for (int e = 0; e < 8; e++) lg[e] += sGW[e*64 + d] * xd;
    }
    // top-2 (strict > keeps lowest index on ties, matching lax.top_k)
    int i1 = 0; float w1v = lg[0];
    #pragma unroll
    for (int e = 1; e < 8; e++){ if (lg[e] > w1v){ w1v = lg[e]; i1 = e; } }
    int i2 = -1; float w2v = -3.0e38f;
    #pragma unroll
    for (int e = 0; e < 8; e++){ if (e != i1 && lg[e] > w2v){ w2v = lg[e]; i2 = e; } }

    // LN1 normalization core (expert-independent): x <- (x - m) * rsqrt(var + eps)
    float s0 = 0.f, s1 = 0.f;
    #pragma unroll
    for (int d = 0; d < 64; d++){ s0 += x[d]; s1 += x[d]*x[d]; }
    float m  = s0 * (1.0f/64.0f);
    float va = s1 * (1.0f/64.0f) - m*m;
    float rs = rsqrtf(va + 1e-5f);
    #pragma unroll
    for (int d = 0; d < 64; d++) x[d] = (x[d] - m) * rs;

    float acc[64];
    #pragma unroll
    for (int d = 0; d < 64; d++) acc[d] = 0.f;

    for (int e = 0; e < 8; e++){
        __syncthreads();   // previous iteration's LDS reads done
        for (int i = tid; i < 8192; i += 256){
            sW1[i] = W1[e*8192 + i];            // [j][d] row-major
            int d = i >> 7, j = i & 127;
            sW2T[j*64 + d] = W2[e*8192 + i];    // W2 [d][j] -> [j][d]
        }
        if (tid < 64){ sL1g[tid] = l1g[e*64+tid]; sL1b[tid] = l1b[e*64+tid]; sB2[tid] = b2[e*64+tid]; }
        if (tid < 128){ sL2g[tid] = l2g[e*128+tid]; sL2b[tid] = l2b[e*128+tid]; }
        __syncthreads();

        const bool a1 = (i1 == e), a2 = (i2 == e);
        if (a1 || a2){   // divergent, but no barriers inside
            const float wt = a1 ? w1v : w2v;

            float g[64];
            #pragma unroll
            for (int d = 0; d < 64; d++) g[d] = gelu_f(x[d]*sL1g[d] + sL1b[d]);

            // pass 1: stats of h (h recomputed in pass 2 to keep VGPRs bounded)
            float hs = 0.f, hs2 = 0.f;
            for (int j = 0; j < 128; j++){
                float hj = dot64(&sW1[j*64], g);
                hs += hj; hs2 += hj*hj;
            }
            float m2  = hs  * (1.0f/128.0f);
            float va2 = hs2 * (1.0f/128.0f) - m2*m2;
            float rs2 = rsqrtf(va2 + 1e-5f);

            #pragma unroll
            for (int d = 0; d < 64; d++) acc[d] += wt * sB2[d];

            // pass 2: recompute h, LN2+gelu, weighted accumulate
            for (int j = 0; j < 128; j++){
                float hj  = dot64(&sW1[j*64], g);
                float ghw = wt * gelu_f((hj - m2)*rs2*sL2g[j] + sL2b[j]);
                const float4* w2t = (const float4*)&sW2T[j*64];
                #pragma unroll
                for (int d4 = 0; d4 < 16; d4++){
                    float4 w = w2t[d4];
                    acc[d4*4+0] += ghw * w.x;
                    acc[d4*4+1] += ghw * w.y;
                    acc[d4*4+2] += ghw * w.z;
                    acc[d4*4+3] += ghw * w.w;
                }
            }
        }
    }

    storef64(out0 + pos, acc);
}

// ---------------- launch ----------------
extern "C" void kernel_launch(void* const* d_in, const int* in_sizes, int n_in,
                              void* d_out, int out_size, void* d_ws, size_t ws_size,
                              hipStream_t stream)
{
    const float* qin = (const float*)d_in[0];
    const float* kin = (const float*)d_in[1];
    const float* vin = (const float*)d_in[2];
    const float* mem = (const float*)d_in[3];
    const float* Wq  = (const float*)d_in[4];
    const float* Wk  = (const float*)d_in[5];
    const float* Wv  = (const float*)d_in[6];
    const float* fg  = (const float*)d_in[7];
    const float* gW  = (const float*)d_in[8];
    const float* gB  = (const float*)d_in[9];
    const float* l1g = (const float*)d_in[10];
    const float* l1b = (const float*)d_in[11];
    const float* W1  = (const float*)d_in[12];
    const float* l2g = (const float*)d_in[13];
    const float* l2b = (const float*)d_in[14];
    const float* W2  = (const float*)d_in[15];
    const float* b2  = (const float*)d_in[16];

    float* out0 = (float*)d_out;                    // token_mixing [B,S,NH*HD]
    float* out1 = out0 + (size_t)NTOK * 64;         // current_memorys [B,NH,S,HD]

    (void)d_ws; (void)ws_size; (void)in_sizes; (void)n_in; (void)out_size;

    k_mem<<<NTOK/256, 256, 0, stream>>>(kin, vin, mem, Wk, Wv, fg, out1);
    k_q  <<<NTOK/256, 256, 0, stream>>>(qin, out1, Wq, out0);
    k_moe<<<NTOK/256, 256, 0, stream>>>(gW, gB, W1, W2, l1g, l1b, l2g, l2b, b2, out0);
}

// Round 4
// 2095.532 us; speedup vs baseline: 1.0253x; 1.0253x over previous
//
#include <hip/hip_runtime.h>
#include <stdint.h>

typedef unsigned short u16;
typedef unsigned int   u32;
typedef unsigned long long u64;

#define B_    8
#define S_    1024
#define HID_  1024
#define NH_   16
#define HD_   64
#define E_    8
#define IDIM_ 128
#define NTOK  (B_*HID_*... )
#undef NTOK
#define NTOK  (B_*NH_*S_)   /* 131072 */
#define NASSIGN (2*NTOK)    /* 262144 top-2 assignments */

// ---------- helpers ----------
__device__ __forceinline__ float bf2f(u16 u){ return __uint_as_float(((u32)u) << 16); }
__device__ __forceinline__ u16 f2bf(float f){
    u32 u = __float_as_uint(f);
    u32 r = u + 0x7fffu + ((u >> 16) & 1u);
    return (u16)(r >> 16);
}
__device__ __forceinline__ void loadf64(const float* __restrict__ p, float* r){
    #pragma unroll
    for (int i = 0; i < 16; i++){
        float4 t = ((const float4*)p)[i];
        r[i*4+0] = t.x; r[i*4+1] = t.y; r[i*4+2] = t.z; r[i*4+3] = t.w;
    }
}
// 64-dot: LDS weight row (float4 broadcast reads) x reg vector, 4 chains for ILP
__device__ __forceinline__ float dot64(const float* __restrict__ w, const float* __restrict__ g){
    float a0=0.f, a1=0.f, a2=0.f, a3=0.f;
    const float4* w4 = (const float4*)w;
    #pragma unroll
    for (int i = 0; i < 16; i++){
        float4 ww = w4[i];
        a0 += ww.x * g[i*4+0];
        a1 += ww.y * g[i*4+1];
        a2 += ww.z * g[i*4+2];
        a3 += ww.w * g[i*4+3];
    }
    return (a0+a1)+(a2+a3);
}
__device__ __forceinline__ float gelu_f(float x){
    return 0.5f * x * (1.0f + erff(x * 0.70710678118654752f));
}

// ---------------- kernel 0: zero counters ----------------
__global__ void k_zero(u32* c){
    if (threadIdx.x < 16) c[threadIdx.x] = 0;
}

// ---------------- kernel 1: k/v projection + memory cell -> current_memorys ----------------
// chunked mv/curv (8 floats at a time) to avoid the 256-float/thread spill of round 2
__global__ __launch_bounds__(256,2) void k_mem(
    const float* __restrict__ kin, const float* __restrict__ vin, const float* __restrict__ mem,
    const float* __restrict__ Wk,  const float* __restrict__ Wv,  const float* __restrict__ fg,
    float* __restrict__ cur_out)
{
    __shared__ float sWk[4096], sWv[4096], sFG[64];
    const int tid = threadIdx.x;
    for (int i = tid; i < 4096; i += 256){ sWk[i] = Wk[i]; sWv[i] = Wv[i]; }
    if (tid < 64) sFG[tid] = fg[tid];
    __syncthreads();

    const int n = blockIdx.x*256 + tid;
    const int s = n & (S_-1), h = (n >> 10) & (NH_-1), b = n >> 14;
    const size_t go = ((size_t)(b*S_ + s))*HID_ + h*HD_;

    float k[64], v[64];
    loadf64(kin + go, k);
    loadf64(vin + go, v);

    const size_t mo = (size_t)n * 64;
    for (int dc = 0; dc < 8; dc++){
        float4 m0 = *(const float4*)(mem + mo + dc*8);
        float4 m1 = *(const float4*)(mem + mo + dc*8 + 4);
        float mv[8] = {m0.x,m0.y,m0.z,m0.w,m1.x,m1.y,m1.z,m1.w};
        float curv[8];
        #pragma unroll
        for (int dd = 0; dd < 8; dd++){
            const int d = dc*8 + dd;
            float kd = dot64(&sWk[d*64], k);
            float vd = dot64(&sWv[d*64], v);
            float f  = sFG[d];
            float cell = kd*vd + f*mv[dd];
            curv[dd] = (1.0f - f)*cell + f*mv[dd];
        }
        float4 o0 = {curv[0],curv[1],curv[2],curv[3]};
        float4 o1 = {curv[4],curv[5],curv[6],curv[7]};
        *(float4*)(cur_out + mo + dc*8) = o0;
        *(float4*)(cur_out + mo + dc*8 + 4) = o1;
    }
}

// ---------------- kernel 2: q projection + x + fused gate/top-2 ----------------
// x written to out0 at its final (bijective) position; topiv/counts only if use_ws
__global__ __launch_bounds__(256,2) void k_q(
    const float* __restrict__ qin, const float* __restrict__ cur_in, const float* __restrict__ Wq,
    const float* __restrict__ gW,  const float* __restrict__ gB,
    float* __restrict__ x_out, uint4* __restrict__ topiv, u32* __restrict__ counts, int use_ws)
{
    __shared__ float sWq[4096], sGW[512], sGB[8];
    const int tid = threadIdx.x;
    for (int i = tid; i < 4096; i += 256) sWq[i] = Wq[i];
    for (int i = tid; i < 512;  i += 256) sGW[i] = gW[i];
    if (tid < 8) sGB[tid] = gB[tid];
    __syncthreads();

    const int n = blockIdx.x*256 + tid;
    const int s = n & (S_-1), h = (n >> 10) & (NH_-1), b = n >> 14;
    const size_t go = ((size_t)(b*S_ + s))*HID_ + h*HD_;

    float q[64];
    loadf64(qin + go, q);

    const size_t mo  = (size_t)n * 64;
    const size_t pos = ((size_t)((b*S_ + s)*NH_ + h)) * 64;

    float lg[8];
    #pragma unroll
    for (int e = 0; e < 8; e++) lg[e] = sGB[e];

    for (int dc = 0; dc < 8; dc++){
        float4 c0 = *(const float4*)(cur_in + mo + dc*8);
        float4 c1 = *(const float4*)(cur_in + mo + dc*8 + 4);
        float cu[8] = {c0.x,c0.y,c0.z,c0.w,c1.x,c1.y,c1.z,c1.w};
        float xv[8];
        #pragma unroll
        for (int dd = 0; dd < 8; dd++){
            const int d = dc*8 + dd;
            float qd = dot64(&sWq[d*64], q);
            float xx = qd * cu[dd];
            xv[dd] = xx;
            #pragma unroll
            for (int e = 0; e < 8; e++) lg[e] += sGW[e*64 + d] * xx;
        }
        float4 o0 = {xv[0],xv[1],xv[2],xv[3]};
        float4 o1 = {xv[4],xv[5],xv[6],xv[7]};
        *(float4*)(x_out + pos + dc*8) = o0;
        *(float4*)(x_out + pos + dc*8 + 4) = o1;
    }

    if (use_ws){
        // top-2 (strict > keeps lowest index on ties, matching lax.top_k)
        int i1 = 0; float v1 = lg[0];
        #pragma unroll
        for (int e = 1; e < 8; e++){ if (lg[e] > v1){ v1 = lg[e]; i1 = e; } }
        int i2 = -1; float v2 = -3.0e38f;
        #pragma unroll
        for (int e = 0; e < 8; e++){ if (e != i1 && lg[e] > v2){ v2 = lg[e]; i2 = e; } }

        topiv[n] = make_uint4((u32)i1, (u32)i2, __float_as_uint(v1), __float_as_uint(v2));

        const int lane = tid & 63;
        for (int e = 0; e < 8; e++){
            u64 m1 = __ballot(i1 == e);
            u64 m2 = __ballot(i2 == e);
            if (lane == 0){
                int c = __popcll(m1) + __popcll(m2);
                if (c) atomicAdd(&counts[e], (u32)c);
            }
        }
    }
}

// ---------------- kernel 3: scatter assignments into compact per-expert lists ----------------
// bucket[slot] = pos32 (out0 row index of the token); slots[n] = (slot1, slot2)
__global__ __launch_bounds__(256,4) void k_scatter(
    const uint4* __restrict__ topiv, const u32* __restrict__ counts, u32* __restrict__ cursors,
    u32* __restrict__ bucket, int2* __restrict__ slots)
{
    const int n = blockIdx.x*256 + threadIdx.x;
    uint4 t = topiv[n];
    const int i1 = (int)t.x, i2 = (int)t.y;

    int off[8]; int acc = 0;
    #pragma unroll
    for (int e = 0; e < 8; e++){ off[e] = acc; acc += (int)counts[e]; }

    const int s = n & (S_-1), h = (n >> 10) & (NH_-1), b = n >> 14;
    const u32 pos32 = (u32)((b*S_ + s)*NH_ + h);

    const int lane = threadIdx.x & 63;
    const u64 low = (1ull << lane) - 1ull;
    int slot1 = 0, slot2 = 0;

    for (int e = 0; e < 8; e++){
        u64 m = __ballot(i1 == e);
        if (i1 == e){
            int leader = __builtin_ctzll(m);
            int base = 0;
            if (lane == leader) base = (int)atomicAdd(&cursors[e], (u32)__popcll(m));
            base = __shfl(base, leader);
            slot1 = off[e] + base + __popcll(m & low);
        }
        u64 m2 = __ballot(i2 == e);
        if (i2 == e){
            int leader = __builtin_ctzll(m2);
            int base = 0;
            if (lane == leader) base = (int)atomicAdd(&cursors[e], (u32)__popcll(m2));
            base = __shfl(base, leader);
            slot2 = off[e] + base + __popcll(m2 & low);
        }
    }
    bucket[slot1] = pos32;
    bucket[slot2] = pos32;
    slots[n] = make_int2(slot1, slot2);
}

// ---------------- kernel 4: compacted expert FFN ----------------
// one block = 256 assignments of ONE expert; h cached as packed bf16 in VGPRs
__global__ __launch_bounds__(256,2) void k_expert(
    const float* __restrict__ x_src, const u32* __restrict__ bucket, const u32* __restrict__ counts,
    const float* __restrict__ W1,  const float* __restrict__ W2,
    const float* __restrict__ l1g, const float* __restrict__ l1b,
    const float* __restrict__ l2g, const float* __restrict__ l2b,
    const float* __restrict__ b2,  u16* __restrict__ aout)
{
    const int e = blockIdx.x >> 9;
    const int c = blockIdx.x & 511;
    const int cnt = (int)counts[e];
    const int aBase = c * 256;
    if (aBase >= cnt) return;     // block-uniform, before any barrier

    int off = 0;
    for (int ee = 0; ee < 8; ee++){ if (ee < e) off += (int)counts[ee]; }

    __shared__ float sW1[8192];        // [j][d] 128x64
    __shared__ float sW2T[128*68];     // [j][d] padded LD=68 (16B-aligned rows, no stride-64 conflicts)
    __shared__ float sL1g[64], sL1b[64], sL2g[128], sL2b[128], sB2[64];
    const int tid = threadIdx.x;
    for (int i = tid; i < 8192; i += 256){
        sW1[i] = W1[e*8192 + i];
        int d = i >> 7, j = i & 127;
        sW2T[j*68 + d] = W2[e*8192 + i];   // W2 [d][j] -> [j][d]
    }
    if (tid < 64){ sL1g[tid] = l1g[e*64+tid]; sL1b[tid] = l1b[e*64+tid]; sB2[tid] = b2[e*64+tid]; }
    if (tid < 128){ sL2g[tid] = l2g[e*128+tid]; sL2b[tid] = l2b[e*128+tid]; }
    __syncthreads();

    const int a = aBase + tid;
    if (a >= cnt) return;
    const u32 pos32 = bucket[off + a];

    float g[64];
    loadf64(x_src + (size_t)pos32*64, g);

    // LN1 + gelu
    float s0 = 0.f, s1 = 0.f;
    #pragma unroll
    for (int d = 0; d < 64; d++){ s0 += g[d]; s1 += g[d]*g[d]; }
    float m  = s0 * (1.0f/64.0f);
    float va = s1 * (1.0f/64.0f) - m*m;
    float rs = rsqrtf(va + 1e-5f);
    #pragma unroll
    for (int d = 0; d < 64; d++) g[d] = gelu_f((g[d]-m)*rs*sL1g[d] + sL1b[d]);

    // pass 1: h = g @ W1^T, stats; cache h as packed bf16 (64 VGPRs)
    u32 hpk[64];
    float hs = 0.f, hs2 = 0.f;
    for (int jp = 0; jp < 64; jp++){
        float h0 = dot64(&sW1[(2*jp  )*64], g);
        float h1 = dot64(&sW1[(2*jp+1)*64], g);
        hs += h0 + h1; hs2 += h0*h0 + h1*h1;
        hpk[jp] = (u32)f2bf(h0) | ((u32)f2bf(h1) << 16);
    }
    float m2  = hs  * (1.0f/128.0f);
    float va2 = hs2 * (1.0f/128.0f) - m2*m2;
    float rs2 = rsqrtf(va2 + 1e-5f);

    // pass 2: LN2+gelu on cached h, accumulate out (g[] regs reused as acc)
    float acc[64];
    #pragma unroll
    for (int d = 0; d < 64; d++) acc[d] = sB2[d];
    for (int j = 0; j < 128; j++){
        float hj = bf2f((u16)((j & 1) ? (hpk[j>>1] >> 16) : (hpk[j>>1] & 0xffffu)));
        float gh = gelu_f((hj - m2)*rs2*sL2g[j] + sL2b[j]);
        const float4* w2t = (const float4*)&sW2T[j*68];
        #pragma unroll
        for (int d4 = 0; d4 < 16; d4++){
            float4 w = w2t[d4];
            acc[d4*4+0] += gh * w.x;
            acc[d4*4+1] += gh * w.y;
            acc[d4*4+2] += gh * w.z;
            acc[d4*4+3] += gh * w.w;
        }
    }

    // store y (bf16) to aout[slot]
    u16* op = aout + (size_t)(off + a) * 64;
    #pragma unroll
    for (int dc = 0; dc < 8; dc++){
        uint4 o;
        o.x = (u32)f2bf(acc[dc*8+0]) | ((u32)f2bf(acc[dc*8+1]) << 16);
        o.y = (u32)f2bf(acc[dc*8+2]) | ((u32)f2bf(acc[dc*8+3]) << 16);
        o.z = (u32)f2bf(acc[dc*8+4]) | ((u32)f2bf(acc[dc*8+5]) << 16);
        o.w = (u32)f2bf(acc[dc*8+6]) | ((u32)f2bf(acc[dc*8+7]) << 16);
        ((uint4*)op)[dc] = o;
    }
}

// ---------------- kernel 5: combine top-2 expert outputs -> out0 (overwrites x) ----------------
// 2D block: 16 tokens x 16 float4-lanes -> coalesced 256B runs
__global__ __launch_bounds__(256,4) void k_combine(
    const u16* __restrict__ aout, const uint4* __restrict__ topiv,
    const int2* __restrict__ slots, float* __restrict__ out0)
{
    const int tid = threadIdx.x;
    const int p   = blockIdx.x*16 + (tid >> 4);   // output row index
    const int cq  = tid & 15;                     // float4 index within row

    // invert p -> token n:  p = (b*S+s)*NH + h ; n = ((b*NH+h)*S + s)
    const int h  = p & (NH_-1);
    const int bs = p >> 4;            // b*S + s
    const int b  = bs >> 10, s = bs & (S_-1);
    const int n  = ((b*NH_ + h) << 10) + s;

    uint4 t = topiv[n];
    float w1 = __uint_as_float(t.z), w2 = __uint_as_float(t.w);
    int2 sl = slots[n];

    uint2 ua = *(const uint2*)(aout + (size_t)sl.x*64 + cq*4);
    uint2 ub = *(const uint2*)(aout + (size_t)sl.y*64 + cq*4);

    float4 o;
    o.x = w1*bf2f((u16)(ua.x & 0xffffu)) + w2*bf2f((u16)(ub.x & 0xffffu));
    o.y = w1*bf2f((u16)(ua.x >> 16))     + w2*bf2f((u16)(ub.x >> 16));
    o.z = w1*bf2f((u16)(ua.y & 0xffffu)) + w2*bf2f((u16)(ub.y & 0xffffu));
    o.w = w1*bf2f((u16)(ua.y >> 16))     + w2*bf2f((u16)(ub.y >> 16));
    *(float4*)(out0 + (size_t)p*64 + cq*4) = o;
}

// ---------------- fallback (round-2 proven k_moe, used only if ws too small) ----------------
__global__ __launch_bounds__(256,2) void k_moe(
    const float* __restrict__ gW,  const float* __restrict__ gB,
    const float* __restrict__ W1,  const float* __restrict__ W2,
    const float* __restrict__ l1g, const float* __restrict__ l1b,
    const float* __restrict__ l2g, const float* __restrict__ l2b,
    const float* __restrict__ b2,  float* __restrict__ out0)
{
    __shared__ float sW1[8192], sW2T[8192];
    __shared__ float sL1g[64], sL1b[64], sL2g[128], sL2b[128], sB2[64];
    __shared__ float sGW[512], sGB[8];
    const int tid = threadIdx.x;

    for (int i = tid; i < 512; i += 256) sGW[i] = gW[i];
    if (tid < 8) sGB[tid] = gB[tid];

    const int n = blockIdx.x*256 + tid;
    const int s = n & (S_-1), h = (n >> 10) & (NH_-1), b = n >> 14;
    const size_t pos = ((size_t)((b*S_ + s)*NH_ + h)) * 64;

    float x[64];
    loadf64(out0 + pos, x);
    __syncthreads();

    float lg[8];
    #pragma unroll
    for (int e = 0; e < 8; e++) lg[e] = sGB[e];
    for (int d = 0; d < 64; d++){
        float xd = x[d];
        #pragma unroll
        for (int e = 0; e < 8; e++) lg[e] += sGW[e*64 + d] * xd;
    }
    int i1 = 0; float w1v = lg[0];
    #pragma unroll
    for (int e = 1; e < 8; e++){ if (lg[e] > w1v){ w1v = lg[e]; i1 = e; } }
    int i2 = -1; float w2v = -3.0e38f;
    #pragma unroll
    for (int e = 0; e < 8; e++){ if (e != i1 && lg[e] > w2v){ w2v = lg[e]; i2 = e; } }

    float s0 = 0.f, s1 = 0.f;
    #pragma unroll
    for (int d = 0; d < 64; d++){ s0 += x[d]; s1 += x[d]*x[d]; }
    float m  = s0 * (1.0f/64.0f);
    float va = s1 * (1.0f/64.0f) - m*m;
    float rs = rsqrtf(va + 1e-5f);
    #pragma unroll
    for (int d = 0; d < 64; d++) x[d] = (x[d] - m) * rs;

    float acc[64];
    #pragma unroll
    for (int d = 0; d < 64; d++) acc[d] = 0.f;

    for (int e = 0; e < 8; e++){
        __syncthreads();
        for (int i = tid; i < 8192; i += 256){
            sW1[i] = W1[e*8192 + i];
            int d = i >> 7, j = i & 127;
            sW2T[j*64 + d] = W2[e*8192 + i];
        }
        if (tid < 64){ sL1g[tid] = l1g[e*64+tid]; sL1b[tid] = l1b[e*64+tid]; sB2[tid] = b2[e*64+tid]; }
        if (tid < 128){ sL2g[tid] = l2g[e*128+tid]; sL2b[tid] = l2b[e*128+tid]; }
        __syncthreads();

        const bool a1 = (i1 == e), a2 = (i2 == e);
        if (a1 || a2){
            const float wt = a1 ? w1v : w2v;
            float g[64];
            #pragma unroll
            for (int d = 0; d < 64; d++) g[d] = gelu_f(x[d]*sL1g[d] + sL1b[d]);
            float hs = 0.f, hs2 = 0.f;
            for (int j = 0; j < 128; j++){
                float hj = dot64(&sW1[j*64], g);
                hs += hj; hs2 += hj*hj;
            }
            float m2  = hs  * (1.0f/128.0f);
            float va2 = hs2 * (1.0f/128.0f) - m2*m2;
            float rs2 = rsqrtf(va2 + 1e-5f);
            #pragma unroll
            for (int d = 0; d < 64; d++) acc[d] += wt * sB2[d];
            for (int j = 0; j < 128; j++){
                float hj  = dot64(&sW1[j*64], g);
                float ghw = wt * gelu_f((hj - m2)*rs2*sL2g[j] + sL2b[j]);
                const float4* w2t = (const float4*)&sW2T[j*64];
                #pragma unroll
                for (int d4 = 0; d4 < 16; d4++){
                    float4 w = w2t[d4];
                    acc[d4*4+0] += ghw * w.x;
                    acc[d4*4+1] += ghw * w.y;
                    acc[d4*4+2] += ghw * w.z;
                    acc[d4*4+3] += ghw * w.w;
                }
            }
        }
    }
    #pragma unroll
    for (int i = 0; i < 16; i++){
        float4 t4; t4.x = acc[i*4+0]; t4.y = acc[i*4+1]; t4.z = acc[i*4+2]; t4.w = acc[i*4+3];
        ((float4*)(out0 + pos))[i] = t4;
    }
}

// ---------------- launch ----------------
extern "C" void kernel_launch(void* const* d_in, const int* in_sizes, int n_in,
                              void* d_out, int out_size, void* d_ws, size_t ws_size,
                              hipStream_t stream)
{
    const float* qin = (const float*)d_in[0];
    const float* kin = (const float*)d_in[1];
    const float* vin = (const float*)d_in[2];
    const float* mem = (const float*)d_in[3];
    const float* Wq  = (const float*)d_in[4];
    const float* Wk  = (const float*)d_in[5];
    const float* Wv  = (const float*)d_in[6];
    const float* fg  = (const float*)d_in[7];
    const float* gW  = (const float*)d_in[8];
    const float* gB  = (const float*)d_in[9];
    const float* l1g = (const float*)d_in[10];
    const float* l1b = (const float*)d_in[11];
    const float* W1  = (const float*)d_in[12];
    const float* l2g = (const float*)d_in[13];
    const float* l2b = (const float*)d_in[14];
    const float* W2  = (const float*)d_in[15];
    const float* b2  = (const float*)d_in[16];

    float* out0 = (float*)d_out;                    // token_mixing [B,S,NH*HD]
    float* out1 = out0 + (size_t)NTOK * 64;         // current_memorys [B,NH,S,HD]

    // ws layout (37.75 MB): aout(bf16) | topiv | slots | bucket | counts+cursors
    char* ws = (char*)d_ws;
    u16*   aout   = (u16*)(ws);                               // 2N*64*2  = 33,554,432
    uint4* topiv  = (uint4*)(ws + (size_t)33554432);          // N*16     =  2,097,152
    int2*  slots  = (int2*)(ws + (size_t)35651584);           // N*8      =  1,048,576
    u32*   bucket = (u32*)(ws + (size_t)36700160);            // 2N*4     =  1,048,576
    u32*   counts = (u32*)(ws + (size_t)37748736);            // 16*4
    u32*   cursors = counts + 8;
    const size_t WS_NEED = 37748736 + 64;
    const int use_ws = (ws_size >= WS_NEED) ? 1 : 0;

    (void)in_sizes; (void)n_in; (void)out_size;

    if (use_ws) k_zero<<<1, 64, 0, stream>>>(counts);
    k_mem<<<NTOK/256, 256, 0, stream>>>(kin, vin, mem, Wk, Wv, fg, out1);
    k_q  <<<NTOK/256, 256, 0, stream>>>(qin, out1, Wq, gW, gB, out0, topiv, counts, use_ws);

    if (use_ws){
        k_scatter<<<NTOK/256, 256, 0, stream>>>(topiv, counts, cursors, bucket, slots);
        k_expert <<<E_*512, 256, 0, stream>>>(out0, bucket, counts, W1, W2, l1g, l1b, l2g, l2b, b2, aout);
        k_combine<<<NTOK/16, 256, 0, stream>>>(aout, topiv, slots, out0);
    } else {
        k_moe<<<NTOK/256, 256, 0, stream>>>(gW, gB, W1, W2, l1g, l1b, l2g, l2b, b2, out0);
    }
}

// Round 5
// 1200.339 us; speedup vs baseline: 1.7900x; 1.7458x over previous
//
#include <hip/hip_runtime.h>
#include <stdint.h>

typedef unsigned short u16;
typedef unsigned int   u32;
typedef unsigned long long u64;
typedef __attribute__((ext_vector_type(8))) short short8;
typedef __attribute__((ext_vector_type(4))) float f32x4;

#define B_    8
#define S_    1024
#define HID_  1024
#define NH_   16
#define HD_   64
#define E_    8
#define IDIM_ 128
#define NTOK  (B_*NH_*S_)   /* 131072 */

// ---------- helpers ----------
__device__ __forceinline__ float bf2f(u16 u){ return __uint_as_float(((u32)u) << 16); }
__device__ __forceinline__ u16 f2bf(float f){
    u32 u = __float_as_uint(f);
    u32 r = u + 0x7fffu + ((u >> 16) & 1u);   // RNE
    return (u16)(r >> 16);
}
// 8 consecutive fp32 -> bf16 MFMA fragment (A or B operand)
__device__ __forceinline__ short8 frag8(const float* __restrict__ p){
    float4 a = *(const float4*)p;
    float4 b = *(const float4*)(p + 4);
    short8 r;
    r[0]=(short)f2bf(a.x); r[1]=(short)f2bf(a.y); r[2]=(short)f2bf(a.z); r[3]=(short)f2bf(a.w);
    r[4]=(short)f2bf(b.x); r[5]=(short)f2bf(b.y); r[6]=(short)f2bf(b.z); r[7]=(short)f2bf(b.w);
    return r;
}
__device__ __forceinline__ float gelu_f(float x){
    return 0.5f * x * (1.0f + erff(x * 0.70710678118654752f));
}

// ---------------- kernel 0: zero counters ----------------
__global__ void k_zero(u32* c){
    if (threadIdx.x < 16) c[threadIdx.x] = 0;
}

// ---------------- kernel 1: MFMA k/v projection + memory cell -> current_memorys ----------------
// grid 512: (b,h,chunk-of-256-tokens); 4 waves/block, each wave 64 tokens x 64 dims.
// No LDS, no per-thread 64-vectors: 4x4 f32x4 accumulators per projection.
// MFMA 16x16x32 bf16 layouts (m89/m91): A[m=lane&15][k=(lane>>4)*8+j],
// B[k=(lane>>4)*8+j][n=lane&15], D col=lane&15, row=(lane>>4)*4+reg.
__global__ __launch_bounds__(256,2) void k_mem(
    const float* __restrict__ kin, const float* __restrict__ vin, const float* __restrict__ mem,
    const float* __restrict__ Wk,  const float* __restrict__ Wv,  const float* __restrict__ fg,
    float* __restrict__ cur_out)
{
    const int lane = threadIdx.x & 63;
    const int wid  = threadIdx.x >> 6;
    const int m    = lane & 15;
    const int kg   = lane >> 4;

    const int slab  = blockIdx.x;
    const int chunk = slab & 3, h = (slab >> 2) & 15, b = slab >> 6;
    const int tw    = chunk*256 + wid*64;   // token (s) base for this wave

    const float* kbase = kin + ((size_t)b*S_)*HID_ + h*64;
    const float* vbase = vin + ((size_t)b*S_)*HID_ + h*64;

    f32x4 accK[4][4], accV[4][4];
    const f32x4 z = {0.f,0.f,0.f,0.f};
    #pragma unroll
    for (int i=0;i<4;i++){ accK[i][0]=z;accK[i][1]=z;accK[i][2]=z;accK[i][3]=z;
                           accV[i][0]=z;accV[i][1]=z;accV[i][2]=z;accV[i][3]=z; }

    // K projection
    #pragma unroll
    for (int kk=0; kk<2; kk++){
        const int k0 = kk*32 + kg*8;
        short8 aF[4], bF[4];
        #pragma unroll
        for (int mt=0; mt<4; mt++) aF[mt] = frag8(kbase + (size_t)(tw + mt*16 + m)*HID_ + k0);
        #pragma unroll
        for (int ct=0; ct<4; ct++) bF[ct] = frag8(Wk + (ct*16 + m)*64 + k0);
        #pragma unroll
        for (int mt=0; mt<4; mt++)
            #pragma unroll
            for (int ct=0; ct<4; ct++)
                accK[mt][ct] = __builtin_amdgcn_mfma_f32_16x16x32_bf16(aF[mt], bF[ct], accK[mt][ct], 0,0,0);
    }
    // V projection
    #pragma unroll
    for (int kk=0; kk<2; kk++){
        const int k0 = kk*32 + kg*8;
        short8 aF[4], bF[4];
        #pragma unroll
        for (int mt=0; mt<4; mt++) aF[mt] = frag8(vbase + (size_t)(tw + mt*16 + m)*HID_ + k0);
        #pragma unroll
        for (int ct=0; ct<4; ct++) bF[ct] = frag8(Wv + (ct*16 + m)*64 + k0);
        #pragma unroll
        for (int mt=0; mt<4; mt++)
            #pragma unroll
            for (int ct=0; ct<4; ct++)
                accV[mt][ct] = __builtin_amdgcn_mfma_f32_16x16x32_bf16(aF[mt], bF[ct], accV[mt][ct], 0,0,0);
    }

    // epilogue: lane holds D[row = kg*4 + r][col = ct*16 + m] per tile mt
    const size_t nb = ((size_t)(b*NH_ + h)) << 10;   // global token base of (b,h)
    float fgv[4];
    #pragma unroll
    for (int ct=0; ct<4; ct++) fgv[ct] = fg[ct*16 + m];

    #pragma unroll
    for (int mt=0; mt<4; mt++){
        #pragma unroll
        for (int r=0; r<4; r++){
            const int tok = tw + mt*16 + kg*4 + r;
            const size_t rowo = (nb + (size_t)tok)*64;
            #pragma unroll
            for (int ct=0; ct<4; ct++){
                const int d = ct*16 + m;
                const float kd = accK[mt][ct][r];
                const float vd = accV[mt][ct][r];
                const float f  = fgv[ct];
                const float mv = mem[rowo + d];
                const float cell = kd*vd + f*mv;
                cur_out[rowo + d] = (1.0f - f)*cell + f*mv;
            }
        }
    }
}

// ---------------- kernel 2: MFMA q projection; x = q_*cur -> out0 at final pos ----------------
__global__ __launch_bounds__(256,2) void k_q(
    const float* __restrict__ qin, const float* __restrict__ cur_in, const float* __restrict__ Wq,
    float* __restrict__ out0)
{
    const int lane = threadIdx.x & 63;
    const int wid  = threadIdx.x >> 6;
    const int m    = lane & 15;
    const int kg   = lane >> 4;

    const int slab  = blockIdx.x;
    const int chunk = slab & 3, h = (slab >> 2) & 15, b = slab >> 6;
    const int tw    = chunk*256 + wid*64;

    const float* qbase = qin + ((size_t)b*S_)*HID_ + h*64;

    f32x4 accQ[4][4];
    const f32x4 z = {0.f,0.f,0.f,0.f};
    #pragma unroll
    for (int i=0;i<4;i++){ accQ[i][0]=z;accQ[i][1]=z;accQ[i][2]=z;accQ[i][3]=z; }

    #pragma unroll
    for (int kk=0; kk<2; kk++){
        const int k0 = kk*32 + kg*8;
        short8 aF[4], bF[4];
        #pragma unroll
        for (int mt=0; mt<4; mt++) aF[mt] = frag8(qbase + (size_t)(tw + mt*16 + m)*HID_ + k0);
        #pragma unroll
        for (int ct=0; ct<4; ct++) bF[ct] = frag8(Wq + (ct*16 + m)*64 + k0);
        #pragma unroll
        for (int mt=0; mt<4; mt++)
            #pragma unroll
            for (int ct=0; ct<4; ct++)
                accQ[mt][ct] = __builtin_amdgcn_mfma_f32_16x16x32_bf16(aF[mt], bF[ct], accQ[mt][ct], 0,0,0);
    }

    const size_t nb = ((size_t)(b*NH_ + h)) << 10;
    #pragma unroll
    for (int mt=0; mt<4; mt++){
        #pragma unroll
        for (int r=0; r<4; r++){
            const int tok = tw + mt*16 + kg*4 + r;
            const size_t curo = (nb + (size_t)tok)*64;
            const size_t po   = ((size_t)(b*S_ + tok)*NH_ + h)*64;
            #pragma unroll
            for (int ct=0; ct<4; ct++){
                const int d = ct*16 + m;
                out0[po + d] = accQ[mt][ct][r] * cur_in[curo + d];
            }
        }
    }
}

// ---------------- kernel 3: gate logits + top-2 (streaming, no x[64] resident) ----------------
__global__ __launch_bounds__(256,2) void k_gate(
    const float* __restrict__ x_src, const float* __restrict__ gW, const float* __restrict__ gB,
    uint4* __restrict__ topiv, u32* __restrict__ counts)
{
    __shared__ float sGW[512], sGB[8];
    const int tid = threadIdx.x;
    for (int i = tid; i < 512; i += 256) sGW[i] = gW[i];
    if (tid < 8) sGB[tid] = gB[tid];
    __syncthreads();

    const int n = blockIdx.x*256 + tid;
    const int s = n & (S_-1), h = (n >> 10) & (NH_-1), b = n >> 14;
    const size_t po = ((size_t)(b*S_ + s)*NH_ + h)*64;

    float lg[8];
    #pragma unroll
    for (int e = 0; e < 8; e++) lg[e] = sGB[e];

    for (int dc = 0; dc < 16; dc++){
        float4 x4 = ((const float4*)(x_src + po))[dc];
        float xv[4] = {x4.x, x4.y, x4.z, x4.w};
        #pragma unroll
        for (int i = 0; i < 4; i++){
            const int d = dc*4 + i;
            #pragma unroll
            for (int e = 0; e < 8; e++) lg[e] += sGW[e*64 + d] * xv[i];
        }
    }

    // top-2 (strict > keeps lowest index on ties, matching lax.top_k)
    int i1 = 0; float v1 = lg[0];
    #pragma unroll
    for (int e = 1; e < 8; e++){ if (lg[e] > v1){ v1 = lg[e]; i1 = e; } }
    int i2 = -1; float v2 = -3.0e38f;
    #pragma unroll
    for (int e = 0; e < 8; e++){ if (e != i1 && lg[e] > v2){ v2 = lg[e]; i2 = e; } }

    topiv[n] = make_uint4((u32)i1, (u32)i2, __float_as_uint(v1), __float_as_uint(v2));

    const int lane = tid & 63;
    for (int e = 0; e < 8; e++){
        u64 m1 = __ballot(i1 == e);
        u64 m2 = __ballot(i2 == e);
        if (lane == 0){
            int c = __popcll(m1) + __popcll(m2);
            if (c) atomicAdd(&counts[e], (u32)c);
        }
    }
}

// ---------------- kernel 4: scatter assignments into compact per-expert lists ----------------
__global__ __launch_bounds__(256,4) void k_scatter(
    const uint4* __restrict__ topiv, const u32* __restrict__ counts, u32* __restrict__ cursors,
    u32* __restrict__ bucket, int2* __restrict__ slots)
{
    const int n = blockIdx.x*256 + threadIdx.x;
    uint4 t = topiv[n];
    const int i1 = (int)t.x, i2 = (int)t.y;

    int off[8]; int acc = 0;
    #pragma unroll
    for (int e = 0; e < 8; e++){ off[e] = acc; acc += (int)counts[e]; }

    const int s = n & (S_-1), h = (n >> 10) & (NH_-1), b = n >> 14;
    const u32 pos32 = (u32)((b*S_ + s)*NH_ + h);

    const int lane = threadIdx.x & 63;
    const u64 low = (1ull << lane) - 1ull;
    int slot1 = 0, slot2 = 0;

    for (int e = 0; e < 8; e++){
        u64 m = __ballot(i1 == e);
        if (i1 == e){
            int leader = __builtin_ctzll(m);
            int base = 0;
            if (lane == leader) base = (int)atomicAdd(&cursors[e], (u32)__popcll(m));
            base = __shfl(base, leader);
            slot1 = off[e] + base + __popcll(m & low);
        }
        u64 m2 = __ballot(i2 == e);
        if (i2 == e){
            int leader = __builtin_ctzll(m2);
            int base = 0;
            if (lane == leader) base = (int)atomicAdd(&cursors[e], (u32)__popcll(m2));
            base = __shfl(base, leader);
            slot2 = off[e] + base + __popcll(m2 & low);
        }
    }
    bucket[slot1] = pos32;
    bucket[slot2] = pos32;
    slots[n] = make_int2(slot1, slot2);
}

// ---------------- kernel 5: compacted expert FFN (unchanged from round 4) ----------------
__global__ __launch_bounds__(256,2) void k_expert(
    const float* __restrict__ x_src, const u32* __restrict__ bucket, const u32* __restrict__ counts,
    const float* __restrict__ W1,  const float* __restrict__ W2,
    const float* __restrict__ l1g, const float* __restrict__ l1b,
    const float* __restrict__ l2g, const float* __restrict__ l2b,
    const float* __restrict__ b2,  u16* __restrict__ aout)
{
    const int e = blockIdx.x >> 9;
    const int c = blockIdx.x & 511;
    const int cnt = (int)counts[e];
    const int aBase = c * 256;
    if (aBase >= cnt) return;     // block-uniform, before any barrier

    int off = 0;
    for (int ee = 0; ee < 8; ee++){ if (ee < e) off += (int)counts[ee]; }

    __shared__ float sW1[8192];        // [j][d] 128x64
    __shared__ float sW2T[128*68];     // [j][d] padded LD=68
    __shared__ float sL1g[64], sL1b[64], sL2g[128], sL2b[128], sB2[64];
    const int tid = threadIdx.x;
    for (int i = tid; i < 8192; i += 256){
        sW1[i] = W1[e*8192 + i];
        int d = i >> 7, j = i & 127;
        sW2T[j*68 + d] = W2[e*8192 + i];
    }
    if (tid < 64){ sL1g[tid] = l1g[e*64+tid]; sL1b[tid] = l1b[e*64+tid]; sB2[tid] = b2[e*64+tid]; }
    if (tid < 128){ sL2g[tid] = l2g[e*128+tid]; sL2b[tid] = l2b[e*128+tid]; }
    __syncthreads();

    const int a = aBase + tid;
    if (a >= cnt) return;
    const u32 pos32 = bucket[off + a];

    float g[64];
    #pragma unroll
    for (int i = 0; i < 16; i++){
        float4 t = ((const float4*)(x_src + (size_t)pos32*64))[i];
        g[i*4+0]=t.x; g[i*4+1]=t.y; g[i*4+2]=t.z; g[i*4+3]=t.w;
    }

    float s0 = 0.f, s1 = 0.f;
    #pragma unroll
    for (int d = 0; d < 64; d++){ s0 += g[d]; s1 += g[d]*g[d]; }
    float m  = s0 * (1.0f/64.0f);
    float va = s1 * (1.0f/64.0f) - m*m;
    float rs = rsqrtf(va + 1e-5f);
    #pragma unroll
    for (int d = 0; d < 64; d++) g[d] = gelu_f((g[d]-m)*rs*sL1g[d] + sL1b[d]);

    u32 hpk[64];
    float hs = 0.f, hs2 = 0.f;
    for (int jp = 0; jp < 64; jp++){
        float h0, h1;
        {
            float a0=0.f,a1=0.f,a2=0.f,a3=0.f;
            const float4* w4 = (const float4*)&sW1[(2*jp)*64];
            #pragma unroll
            for (int i = 0; i < 16; i++){
                float4 ww = w4[i];
                a0 += ww.x*g[i*4+0]; a1 += ww.y*g[i*4+1]; a2 += ww.z*g[i*4+2]; a3 += ww.w*g[i*4+3];
            }
            h0 = (a0+a1)+(a2+a3);
        }
        {
            float a0=0.f,a1=0.f,a2=0.f,a3=0.f;
            const float4* w4 = (const float4*)&sW1[(2*jp+1)*64];
            #pragma unroll
            for (int i = 0; i < 16; i++){
                float4 ww = w4[i];
                a0 += ww.x*g[i*4+0]; a1 += ww.y*g[i*4+1]; a2 += ww.z*g[i*4+2]; a3 += ww.w*g[i*4+3];
            }
            h1 = (a0+a1)+(a2+a3);
        }
        hs += h0 + h1; hs2 += h0*h0 + h1*h1;
        hpk[jp] = (u32)f2bf(h0) | ((u32)f2bf(h1) << 16);
    }
    float m2  = hs  * (1.0f/128.0f);
    float va2 = hs2 * (1.0f/128.0f) - m2*m2;
    float rs2 = rsqrtf(va2 + 1e-5f);

    float acc[64];
    #pragma unroll
    for (int d = 0; d < 64; d++) acc[d] = sB2[d];
    for (int j = 0; j < 128; j++){
        float hj = bf2f((u16)((j & 1) ? (hpk[j>>1] >> 16) : (hpk[j>>1] & 0xffffu)));
        float gh = gelu_f((hj - m2)*rs2*sL2g[j] + sL2b[j]);
        const float4* w2t = (const float4*)&sW2T[j*68];
        #pragma unroll
        for (int d4 = 0; d4 < 16; d4++){
            float4 w = w2t[d4];
            acc[d4*4+0] += gh * w.x;
            acc[d4*4+1] += gh * w.y;
            acc[d4*4+2] += gh * w.z;
            acc[d4*4+3] += gh * w.w;
        }
    }

    u16* op = aout + (size_t)(off + a) * 64;
    #pragma unroll
    for (int dc = 0; dc < 8; dc++){
        uint4 o;
        o.x = (u32)f2bf(acc[dc*8+0]) | ((u32)f2bf(acc[dc*8+1]) << 16);
        o.y = (u32)f2bf(acc[dc*8+2]) | ((u32)f2bf(acc[dc*8+3]) << 16);
        o.z = (u32)f2bf(acc[dc*8+4]) | ((u32)f2bf(acc[dc*8+5]) << 16);
        o.w = (u32)f2bf(acc[dc*8+6]) | ((u32)f2bf(acc[dc*8+7]) << 16);
        ((uint4*)op)[dc] = o;
    }
}

// ---------------- kernel 6: combine top-2 expert outputs -> out0 (overwrites x) ----------------
__global__ __launch_bounds__(256,4) void k_combine(
    const u16* __restrict__ aout, const uint4* __restrict__ topiv,
    const int2* __restrict__ slots, float* __restrict__ out0)
{
    const int tid = threadIdx.x;
    const int p   = blockIdx.x*16 + (tid >> 4);
    const int cq  = tid & 15;

    const int h  = p & (NH_-1);
    const int bs = p >> 4;
    const int b  = bs >> 10, s = bs & (S_-1);
    const int n  = ((b*NH_ + h) << 10) + s;

    uint4 t = topiv[n];
    float w1 = __uint_as_float(t.z), w2 = __uint_as_float(t.w);
    int2 sl = slots[n];

    uint2 ua = *(const uint2*)(aout + (size_t)sl.x*64 + cq*4);
    uint2 ub = *(const uint2*)(aout + (size_t)sl.y*64 + cq*4);

    float4 o;
    o.x = w1*bf2f((u16)(ua.x & 0xffffu)) + w2*bf2f((u16)(ub.x & 0xffffu));
    o.y = w1*bf2f((u16)(ua.x >> 16))     + w2*bf2f((u16)(ub.x >> 16));
    o.z = w1*bf2f((u16)(ua.y & 0xffffu)) + w2*bf2f((u16)(ub.y & 0xffffu));
    o.w = w1*bf2f((u16)(ua.y >> 16))     + w2*bf2f((u16)(ub.y >> 16));
    *(float4*)(out0 + (size_t)p*64 + cq*4) = o;
}

// ---------------- launch ----------------
extern "C" void kernel_launch(void* const* d_in, const int* in_sizes, int n_in,
                              void* d_out, int out_size, void* d_ws, size_t ws_size,
                              hipStream_t stream)
{
    const float* qin = (const float*)d_in[0];
    const float* kin = (const float*)d_in[1];
    const float* vin = (const float*)d_in[2];
    const float* mem = (const float*)d_in[3];
    const float* Wq  = (const float*)d_in[4];
    const float* Wk  = (const float*)d_in[5];
    const float* Wv  = (const float*)d_in[6];
    const float* fg  = (const float*)d_in[7];
    const float* gW  = (const float*)d_in[8];
    const float* gB  = (const float*)d_in[9];
    const float* l1g = (const float*)d_in[10];
    const float* l1b = (const float*)d_in[11];
    const float* W1  = (const float*)d_in[12];
    const float* l2g = (const float*)d_in[13];
    const float* l2b = (const float*)d_in[14];
    const float* W2  = (const float*)d_in[15];
    const float* b2  = (const float*)d_in[16];

    float* out0 = (float*)d_out;                    // token_mixing [B,S,NH*HD]
    float* out1 = out0 + (size_t)NTOK * 64;         // current_memorys [B,NH,S,HD]

    // ws layout (37.75 MB, proven sufficient in round 4: compacted path ran)
    char* ws = (char*)d_ws;
    u16*   aout   = (u16*)(ws);                               // 2N*64*2  = 33,554,432
    uint4* topiv  = (uint4*)(ws + (size_t)33554432);          // N*16     =  2,097,152
    int2*  slots  = (int2*)(ws + (size_t)35651584);           // N*8      =  1,048,576
    u32*   bucket = (u32*)(ws + (size_t)36700160);            // 2N*4     =  1,048,576
    u32*   counts = (u32*)(ws + (size_t)37748736);            // 16*4
    u32*   cursors = counts + 8;

    (void)in_sizes; (void)n_in; (void)out_size; (void)ws_size;

    k_zero   <<<1, 64, 0, stream>>>(counts);
    k_mem    <<<512, 256, 0, stream>>>(kin, vin, mem, Wk, Wv, fg, out1);
    k_q      <<<512, 256, 0, stream>>>(qin, out1, Wq, out0);
    k_gate   <<<NTOK/256, 256, 0, stream>>>(out0, gW, gB, topiv, counts);
    k_scatter<<<NTOK/256, 256, 0, stream>>>(topiv, counts, cursors, bucket, slots);
    k_expert <<<E_*512, 256, 0, stream>>>(out0, bucket, counts, W1, W2, l1g, l1b, l2g, l2b, b2, aout);
    k_combine<<<NTOK/16, 256, 0, stream>>>(aout, topiv, slots, out0);
}